// Round 1
// baseline (1303.929 us; speedup 1.0000x reference)
//
#include <hip/hip_runtime.h>

// Problem constants (B,S,E,H fixed by the reference)
constexpr int Bc = 2, Sc = 2048, Ec = 1024, Hc = 16, DKc = 64;

typedef __attribute__((ext_vector_type(8))) __bf16 bf16x8;
typedef __attribute__((ext_vector_type(4))) float f32x4;
typedef __attribute__((ext_vector_type(8))) unsigned short u16x8;

__device__ __forceinline__ unsigned short f2bf(float f) {
  union { float f; unsigned u; } c; c.f = f;
  unsigned u = c.u;
  return (unsigned short)((u + 0x7fffu + ((u >> 16) & 1u)) >> 16);
}

// ---------------- convert x (fp32 -> bf16), 8 elems/thread ----------------
__global__ __launch_bounds__(256) void cvt_x_k(const float* __restrict__ in,
                                               unsigned short* __restrict__ out) {
  int i = blockIdx.x * 256 + threadIdx.x;
  const f32x4* p = (const f32x4*)in;
  f32x4 a = p[i * 2], b = p[i * 2 + 1];
  u16x8 o;
  o[0] = f2bf(a[0]); o[1] = f2bf(a[1]); o[2] = f2bf(a[2]); o[3] = f2bf(a[3]);
  o[4] = f2bf(b[0]); o[5] = f2bf(b[1]); o[6] = f2bf(b[2]); o[7] = f2bf(b[3]);
  ((u16x8*)out)[i] = o;
}

// ------------- transpose + convert W (fp32 [K,N] -> bf16 [N,K]) -----------
__global__ __launch_bounds__(256) void cvt_wt_k(const float* __restrict__ W,
                                                unsigned short* __restrict__ WT) {
  __shared__ float t[32][33];
  int tx = threadIdx.x & 31, ty = threadIdx.x >> 5;  // 32 x 8
  int n0 = blockIdx.x * 32, k0 = blockIdx.y * 32;
#pragma unroll
  for (int i = 0; i < 4; ++i)
    t[ty * 4 + i][tx] = W[(size_t)(k0 + ty * 4 + i) * Ec + n0 + tx];
  __syncthreads();
#pragma unroll
  for (int i = 0; i < 4; ++i)
    WT[(size_t)(n0 + ty * 4 + i) * Ec + k0 + tx] = f2bf(t[tx][ty * 4 + i]);
}

// ---------------------------------------------------------------------------
// Generic batched MFMA GEMM: C = A[M,K] @ B^T[N,K]  (B passed as [N,K] bf16)
// A is bf16 (AF32=false) or fp32 (AF32=true, converted to bf16 fragments).
// Batch index z decomposed as zb=z>>4, zh=z&15; base offsets via strides.
// EPI: 0 = bf16 out (+bias), normal orient, C += zb*cStrB + zh*cStrH
//      1 = bf16 out transposed into Vt[B][H][DK][S]  (+bias by col)
//      2 = fp32 out * scale (scores)
//      3 = fp32 out + bias (final)
// Tile: BMxBNx32, 4 waves (2x2), wave tile (BM/2)x(BN/2), 16x16x32 MFMA.
// ---------------------------------------------------------------------------
template <int BM, int BN, bool AF32, int EPI>
__global__ __launch_bounds__(256) void gemm_k(
    const void* __restrict__ Ap, const unsigned short* __restrict__ Bp,
    void* __restrict__ Cp, const float* __restrict__ bias,
    int M, int N, int K, int lda, int ldb, int ldc,
    long aStrB, long aStrH, long bStrB, long bStrH,
    long cStrB, long cStrH, float scale) {
  constexpr int BK = 32;
  constexpr int WM = BM / 2, WN = BN / 2;
  constexpr int MF = WM / 16, NF = WN / 16;
  constexpr int AE = AF32 ? 4 : 2;

  __shared__ __align__(16) unsigned char smem[BM * BK * AE + BN * BK * 2];
  unsigned char* sA = smem;
  unsigned char* sB = smem + BM * BK * AE;

  const int tid = threadIdx.x;
  const int lane = tid & 63;
  const int wv = tid >> 6;
  const int wr = wv >> 1, wc = wv & 1;
  const int zb = blockIdx.z >> 4, zh = blockIdx.z & 15;
  const int m0 = blockIdx.y * BM, n0 = blockIdx.x * BN;

  const float* Af = (const float*)Ap + (size_t)(zb * aStrB + zh * aStrH);
  const unsigned short* Au = (const unsigned short*)Ap + (size_t)(zb * aStrB + zh * aStrH);
  const unsigned short* Bu = Bp + (size_t)(zb * bStrB + zh * bStrH);

  f32x4 acc[MF][NF] = {};

  constexpr int ASPR = BK * AE / 16;        // 16B segments per A row (4 or 8)
  constexpr int APER = BM * ASPR / 256;     // A segments per thread
  constexpr int BPER = BN * 4 / 256;        // B segments per thread (bf16)

  for (int k0 = 0; k0 < K; k0 += BK) {
    __syncthreads();
    // ---- stage A tile [BM][BK] (linear) ----
#pragma unroll
    for (int c = 0; c < APER; ++c) {
      int seg = c * 256 + tid;
      int row = seg / ASPR, sir = seg % ASPR;
      if constexpr (AF32) {
        f32x4 v = *(const f32x4*)(Af + (size_t)(m0 + row) * lda + k0 + sir * 4);
        *(f32x4*)(sA + seg * 16) = v;
      } else {
        u16x8 v = *(const u16x8*)(Au + (size_t)(m0 + row) * lda + k0 + sir * 8);
        *(u16x8*)(sA + seg * 16) = v;
      }
    }
    // ---- stage B tile [BN][BK] (linear bf16) ----
#pragma unroll
    for (int c = 0; c < BPER; ++c) {
      int seg = c * 256 + tid;
      int row = seg >> 2, sir = seg & 3;
      u16x8 v = *(const u16x8*)(Bu + (size_t)(n0 + row) * ldb + k0 + sir * 8);
      *(u16x8*)(sB + seg * 16) = v;
    }
    __syncthreads();

    const int kq = (lane >> 4) * 8;
    const int lr = lane & 15;
    bf16x8 av[MF], bw[NF];
#pragma unroll
    for (int m = 0; m < MF; ++m) {
      int row = wr * WM + m * 16 + lr;
      if constexpr (AF32) {
        const float* p = (const float*)sA + (size_t)row * BK + kq;
        bf16x8 t;
#pragma unroll
        for (int j = 0; j < 8; ++j) t[j] = (__bf16)p[j];
        av[m] = t;
      } else {
        av[m] = *(const bf16x8*)(sA + ((size_t)row * BK + kq) * 2);
      }
    }
#pragma unroll
    for (int n = 0; n < NF; ++n) {
      int row = wc * WN + n * 16 + lr;
      bw[n] = *(const bf16x8*)(sB + ((size_t)row * BK + kq) * 2);
    }
#pragma unroll
    for (int m = 0; m < MF; ++m)
#pragma unroll
      for (int n = 0; n < NF; ++n)
        acc[m][n] = __builtin_amdgcn_mfma_f32_16x16x32_bf16(av[m], bw[n], acc[m][n], 0, 0, 0);
  }

  // ---- epilogue ----
  const int r4 = (lane >> 4) * 4, cl = lane & 15;
#pragma unroll
  for (int m = 0; m < MF; ++m) {
#pragma unroll
    for (int n = 0; n < NF; ++n) {
#pragma unroll
      for (int i = 0; i < 4; ++i) {
        int row = m0 + wr * WM + m * 16 + r4 + i;
        int col = n0 + wc * WN + n * 16 + cl;
        float v = acc[m][n][i];
        if constexpr (EPI == 0) {
          unsigned short* C = (unsigned short*)Cp + (size_t)(zb * cStrB + zh * cStrH);
          if (bias) v += bias[col];
          C[(size_t)row * ldc + col] = f2bf(v);
        } else if constexpr (EPI == 1) {
          // Vt[b][h][d][s]: linear index b*E*S + col*S + s, col = h*64+d
          unsigned short* C = (unsigned short*)Cp;
          if (bias) v += bias[col];
          int b = row >> 11, s = row & (Sc - 1);
          C[(size_t)b * Ec * Sc + (size_t)col * Sc + s] = f2bf(v);
        } else if constexpr (EPI == 2) {
          float* C = (float*)Cp + (size_t)(zb * cStrB + zh * cStrH);
          C[(size_t)row * ldc + col] = v * scale;
        } else {
          float* C = (float*)Cp;
          C[(size_t)row * ldc + col] = v + bias[col];
        }
      }
    }
  }
}

// ------------- row softmax over S=2048 + post-softmax mask zeroing ---------
__global__ __launch_bounds__(256) void softmax_mask_k(float* __restrict__ Wt,
                                                      const int* __restrict__ mask) {
  const int q = blockIdx.x;
  const long z = blockIdx.y;  // b*H + h
  float* row = Wt + (z * Sc + q) * (long)Sc;
  const int tid = threadIdx.x;
  const int lane = tid & 63, wv = tid >> 6;

  f32x4 v0 = ((const f32x4*)row)[tid * 2];
  f32x4 v1 = ((const f32x4*)row)[tid * 2 + 1];

  float m = v0[0];
#pragma unroll
  for (int j = 1; j < 4; ++j) m = fmaxf(m, v0[j]);
#pragma unroll
  for (int j = 0; j < 4; ++j) m = fmaxf(m, v1[j]);
#pragma unroll
  for (int off = 32; off; off >>= 1) m = fmaxf(m, __shfl_xor(m, off, 64));

  __shared__ float red[8];
  if (lane == 0) red[wv] = m;
  __syncthreads();
  m = fmaxf(fmaxf(red[0], red[1]), fmaxf(red[2], red[3]));

  float s = 0.f;
#pragma unroll
  for (int j = 0; j < 4; ++j) { v0[j] = __expf(v0[j] - m); s += v0[j]; }
#pragma unroll
  for (int j = 0; j < 4; ++j) { v1[j] = __expf(v1[j] - m); s += v1[j]; }
#pragma unroll
  for (int off = 32; off; off >>= 1) s += __shfl_xor(s, off, 64);
  if (lane == 0) red[4 + wv] = s;
  __syncthreads();
  s = (red[4] + red[5]) + (red[6] + red[7]);
  float inv = 1.f / s;

  const int4* mrow = (const int4*)(mask + (size_t)q * Sc);
  int4 k0 = mrow[tid * 2], k1 = mrow[tid * 2 + 1];
  f32x4 w0, w1;
  w0[0] = k0.x ? v0[0] * inv : 0.f;
  w0[1] = k0.y ? v0[1] * inv : 0.f;
  w0[2] = k0.z ? v0[2] * inv : 0.f;
  w0[3] = k0.w ? v0[3] * inv : 0.f;
  w1[0] = k1.x ? v1[0] * inv : 0.f;
  w1[1] = k1.y ? v1[1] * inv : 0.f;
  w1[2] = k1.z ? v1[2] * inv : 0.f;
  w1[3] = k1.w ? v1[3] * inv : 0.f;
  ((f32x4*)row)[tid * 2] = w0;
  ((f32x4*)row)[tid * 2 + 1] = w1;
}

// ---------------------------------------------------------------------------
extern "C" void kernel_launch(void* const* d_in, const int* in_sizes, int n_in,
                              void* d_out, int out_size, void* d_ws, size_t ws_size,
                              hipStream_t stream) {
  (void)in_sizes; (void)n_in; (void)out_size; (void)ws_size;

  const float* x  = (const float*)d_in[0];
  const int* mask = (const int*)d_in[1];
  const float* Wq = (const float*)d_in[2];
  const float* bq = (const float*)d_in[3];
  const float* Wk = (const float*)d_in[4];
  const float* bk = (const float*)d_in[5];
  const float* Wv = (const float*)d_in[6];
  const float* bv = (const float*)d_in[7];
  const float* Wo = (const float*)d_in[8];
  const float* bo = (const float*)d_in[9];

  float* out = (float*)d_out;
  float* wts = out + (size_t)Bc * Sc * Ec;  // weights output region [B,H,S,S]

  // workspace layout (bf16 tensors), total ~50.3 MB
  unsigned short* xb    = (unsigned short*)d_ws;
  unsigned short* WqT   = xb  + (size_t)Bc * Sc * Ec;
  unsigned short* WkT   = WqT + (size_t)Ec * Ec;
  unsigned short* WvT   = WkT + (size_t)Ec * Ec;
  unsigned short* WoT   = WvT + (size_t)Ec * Ec;
  unsigned short* Qb    = WoT + (size_t)Ec * Ec;
  unsigned short* Kb    = Qb  + (size_t)Bc * Sc * Ec;
  unsigned short* Vt    = Kb  + (size_t)Bc * Sc * Ec;   // [B][H][DK][S]
  unsigned short* attnb = Vt  + (size_t)Bc * Sc * Ec;   // [B*S][E]

  // converts
  cvt_x_k<<<(Bc * Sc * Ec) / 8 / 256, 256, 0, stream>>>(x, xb);
  dim3 tg(Ec / 32, Ec / 32);
  cvt_wt_k<<<tg, 256, 0, stream>>>(Wq, WqT);
  cvt_wt_k<<<tg, 256, 0, stream>>>(Wk, WkT);
  cvt_wt_k<<<tg, 256, 0, stream>>>(Wv, WvT);
  cvt_wt_k<<<tg, 256, 0, stream>>>(Wo, WoT);

  // projections: [4096,1024] @ [1024,1024]^T(-transposed weights) -> bf16
  dim3 gP(Ec / 128, (Bc * Sc) / 128, 1);
  gemm_k<128, 128, false, 0><<<gP, 256, 0, stream>>>(
      xb, WqT, Qb, bq, Bc * Sc, Ec, Ec, Ec, Ec, Ec, 0, 0, 0, 0, 0, 0, 1.f);
  gemm_k<128, 128, false, 0><<<gP, 256, 0, stream>>>(
      xb, WkT, Kb, bk, Bc * Sc, Ec, Ec, Ec, Ec, Ec, 0, 0, 0, 0, 0, 0, 1.f);
  gemm_k<128, 128, false, 1><<<gP, 256, 0, stream>>>(
      xb, WvT, Vt, bv, Bc * Sc, Ec, Ec, Ec, Ec, Ec, 0, 0, 0, 0, 0, 0, 1.f);

  // scores: per (b,h): Q[S,64] @ K[S,64]^T * 0.125 -> fp32 weights region
  dim3 gS(Sc / 128, Sc / 128, Bc * Hc);
  gemm_k<128, 128, false, 2><<<gS, 256, 0, stream>>>(
      Qb, Kb, wts, nullptr, Sc, Sc, DKc, Ec, Ec, Sc,
      (long)Sc * Ec, DKc, (long)Sc * Ec, DKc,
      (long)Hc * Sc * Sc, (long)Sc * Sc, 0.125f);

  // softmax + post-softmax masking (in place on weights region)
  dim3 gSM(Sc, Bc * Hc);
  softmax_mask_k<<<gSM, 256, 0, stream>>>(wts, mask);

  // PV: weights[S,S] (fp32) @ Vt[64,S]^T -> attn bf16 [B*S][E]
  dim3 gPV(1, Sc / 128, Bc * Hc);
  gemm_k<128, 64, true, 0><<<gPV, 256, 0, stream>>>(
      wts, Vt, attnb, nullptr, Sc, DKc, Sc, Sc, Sc, Ec,
      (long)Hc * Sc * Sc, (long)Sc * Sc,
      (long)Hc * DKc * Sc, (long)DKc * Sc,
      (long)Sc * Ec, DKc, 1.f);

  // out = attn @ Wo + bo -> fp32
  gemm_k<128, 128, false, 3><<<gP, 256, 0, stream>>>(
      attnb, WoT, out, bo, Bc * Sc, Ec, Ec, Ec, Ec, Ec, 0, 0, 0, 0, 0, 0, 1.f);
}

// Round 2
// 1109.017 us; speedup vs baseline: 1.1758x; 1.1758x over previous
//
#include <hip/hip_runtime.h>

// Problem constants (B,S,E,H fixed by the reference)
constexpr int Bc = 2, Sc = 2048, Ec = 1024, Hc = 16, DKc = 64;

typedef __attribute__((ext_vector_type(8))) __bf16 bf16x8;
typedef __attribute__((ext_vector_type(4))) float f32x4;
typedef __attribute__((ext_vector_type(8))) unsigned short u16x8;

__device__ __forceinline__ unsigned short f2bf(float f) {
  union { float f; unsigned u; } c; c.f = f;
  unsigned u = c.u;
  return (unsigned short)((u + 0x7fffu + ((u >> 16) & 1u)) >> 16);
}

// ---------------- convert x (fp32 -> bf16), 8 elems/thread ----------------
__global__ __launch_bounds__(256) void cvt_x_k(const float* __restrict__ in,
                                               unsigned short* __restrict__ out) {
  int i = blockIdx.x * 256 + threadIdx.x;
  const f32x4* p = (const f32x4*)in;
  f32x4 a = p[i * 2], b = p[i * 2 + 1];
  u16x8 o;
  o[0] = f2bf(a[0]); o[1] = f2bf(a[1]); o[2] = f2bf(a[2]); o[3] = f2bf(a[3]);
  o[4] = f2bf(b[0]); o[5] = f2bf(b[1]); o[6] = f2bf(b[2]); o[7] = f2bf(b[3]);
  ((u16x8*)out)[i] = o;
}

// ------------- transpose + convert W (fp32 [K,N] -> bf16 [N,K]) -----------
__global__ __launch_bounds__(256) void cvt_wt_k(const float* __restrict__ W,
                                                unsigned short* __restrict__ WT) {
  __shared__ float t[32][33];
  int tx = threadIdx.x & 31, ty = threadIdx.x >> 5;  // 32 x 8
  int n0 = blockIdx.x * 32, k0 = blockIdx.y * 32;
#pragma unroll
  for (int i = 0; i < 4; ++i)
    t[ty * 4 + i][tx] = W[(size_t)(k0 + ty * 4 + i) * Ec + n0 + tx];
  __syncthreads();
#pragma unroll
  for (int i = 0; i < 4; ++i)
    WT[(size_t)(n0 + ty * 4 + i) * Ec + k0 + tx] = f2bf(t[tx][ty * 4 + i]);
}

// ---------------------------------------------------------------------------
// Batched MFMA GEMM: C = A[M,K] @ B^T[N,K]  (B is [N,K] bf16).
// A is bf16 (AF32=false) or fp32 (AF32=true): fp32 A is converted to bf16
// DURING STAGING, so LDS + inner loop are uniformly bf16.
// LDS rows padded to BKP=40 bf16 (80 B stride -> conflict-free-ish b128 reads).
// EPI: 0 = bf16 out (+bias)         1 = bf16 out transposed into Vt[B][H][DK][S]
//      2 = fp32 out * scale         3 = fp32 out + bias
// Tile: BMxBNx32, 4 waves (2x2), wave tile (BM/2)x(BN/2), 16x16x32 MFMA.
// ---------------------------------------------------------------------------
template <int BM, int BN, bool AF32, int EPI>
__global__ __launch_bounds__(256) void gemm_k(
    const void* __restrict__ Ap, const unsigned short* __restrict__ Bp,
    void* __restrict__ Cp, const float* __restrict__ bias,
    int K, int lda, int ldb, int ldc,
    long aStrB, long aStrH, long bStrB, long bStrH,
    long cStrB, long cStrH, float scale) {
  constexpr int BK = 32;
  constexpr int BKP = BK + 8;  // +16B row pad
  constexpr int WM = BM / 2, WN = BN / 2;
  constexpr int MF = WM / 16, NF = WN / 16;

  __shared__ __align__(16) unsigned short smem[(BM + BN) * BKP];
  unsigned short* sA = smem;
  unsigned short* sB = smem + BM * BKP;

  const int tid = threadIdx.x;
  const int lane = tid & 63;
  const int wv = tid >> 6;
  const int wr = wv >> 1, wc = wv & 1;
  const int zb = blockIdx.z >> 4, zh = blockIdx.z & 15;
  const int m0 = blockIdx.y * BM, n0 = blockIdx.x * BN;

  const float* Af = (const float*)Ap + (size_t)(zb * aStrB + zh * aStrH);
  const unsigned short* Au = (const unsigned short*)Ap + (size_t)(zb * aStrB + zh * aStrH);
  const unsigned short* Bu = Bp + (size_t)(zb * bStrB + zh * bStrH);

  f32x4 acc[MF][NF] = {};

  constexpr int APER = BM * 4 / 256;  // 16B bf16 LDS segs per thread (A)
  constexpr int BPER = BN * 4 / 256;

  for (int k0 = 0; k0 < K; k0 += BK) {
    __syncthreads();
    // ---- stage A tile [BM][BK] as bf16 (convert fp32 on the fly) ----
#pragma unroll
    for (int c = 0; c < APER; ++c) {
      int seg = c * 256 + tid;
      int row = seg >> 2, sir = seg & 3;
      u16x8 o;
      if constexpr (AF32) {
        const float* p = Af + (size_t)(m0 + row) * lda + k0 + sir * 8;
        f32x4 v0 = *(const f32x4*)p, v1 = *(const f32x4*)(p + 4);
        o[0] = f2bf(v0[0]); o[1] = f2bf(v0[1]); o[2] = f2bf(v0[2]); o[3] = f2bf(v0[3]);
        o[4] = f2bf(v1[0]); o[5] = f2bf(v1[1]); o[6] = f2bf(v1[2]); o[7] = f2bf(v1[3]);
      } else {
        o = *(const u16x8*)(Au + (size_t)(m0 + row) * lda + k0 + sir * 8);
      }
      *(u16x8*)(sA + row * BKP + sir * 8) = o;
    }
    // ---- stage B tile [BN][BK] bf16 ----
#pragma unroll
    for (int c = 0; c < BPER; ++c) {
      int seg = c * 256 + tid;
      int row = seg >> 2, sir = seg & 3;
      u16x8 v = *(const u16x8*)(Bu + (size_t)(n0 + row) * ldb + k0 + sir * 8);
      *(u16x8*)(sB + row * BKP + sir * 8) = v;
    }
    __syncthreads();

    const int kq = (lane >> 4) * 8;
    const int lr = lane & 15;
    bf16x8 av[MF], bw[NF];
#pragma unroll
    for (int m = 0; m < MF; ++m)
      av[m] = *(const bf16x8*)(sA + (wr * WM + m * 16 + lr) * BKP + kq);
#pragma unroll
    for (int n = 0; n < NF; ++n)
      bw[n] = *(const bf16x8*)(sB + (wc * WN + n * 16 + lr) * BKP + kq);
#pragma unroll
    for (int m = 0; m < MF; ++m)
#pragma unroll
      for (int n = 0; n < NF; ++n)
        acc[m][n] = __builtin_amdgcn_mfma_f32_16x16x32_bf16(av[m], bw[n], acc[m][n], 0, 0, 0);
  }

  // ---- epilogue ----
  const int r4 = (lane >> 4) * 4, cl = lane & 15;
#pragma unroll
  for (int m = 0; m < MF; ++m) {
#pragma unroll
    for (int n = 0; n < NF; ++n) {
#pragma unroll
      for (int i = 0; i < 4; ++i) {
        int row = m0 + wr * WM + m * 16 + r4 + i;
        int col = n0 + wc * WN + n * 16 + cl;
        float v = acc[m][n][i];
        if constexpr (EPI == 0) {
          unsigned short* C = (unsigned short*)Cp + (size_t)(zb * cStrB + zh * cStrH);
          if (bias) v += bias[col];
          C[(size_t)row * ldc + col] = f2bf(v);
        } else if constexpr (EPI == 1) {
          // Vt[b][h][d][s]: b*E*S + col*S + s, col = h*64+d
          unsigned short* C = (unsigned short*)Cp;
          if (bias) v += bias[col];
          int b = row >> 11, s = row & (Sc - 1);
          C[(size_t)b * Ec * Sc + (size_t)col * Sc + s] = f2bf(v);
        } else if constexpr (EPI == 2) {
          float* C = (float*)Cp + (size_t)(zb * cStrB + zh * cStrH);
          C[(size_t)row * ldc + col] = v * scale;
        } else {
          float* C = (float*)Cp;
          C[(size_t)row * ldc + col] = v + bias[col];
        }
      }
    }
  }
}

// ------------- row softmax over S=2048 + post-softmax mask zeroing ---------
__global__ __launch_bounds__(256) void softmax_mask_k(float* __restrict__ Wt,
                                                      const int* __restrict__ mask) {
  const int q = blockIdx.x;
  const long z = blockIdx.y;  // b*H + h
  float* row = Wt + (z * Sc + q) * (long)Sc;
  const int tid = threadIdx.x;
  const int lane = tid & 63, wv = tid >> 6;

  f32x4 v0 = ((const f32x4*)row)[tid * 2];
  f32x4 v1 = ((const f32x4*)row)[tid * 2 + 1];

  float m = v0[0];
#pragma unroll
  for (int j = 1; j < 4; ++j) m = fmaxf(m, v0[j]);
#pragma unroll
  for (int j = 0; j < 4; ++j) m = fmaxf(m, v1[j]);
#pragma unroll
  for (int off = 32; off; off >>= 1) m = fmaxf(m, __shfl_xor(m, off, 64));

  __shared__ float red[8];
  if (lane == 0) red[wv] = m;
  __syncthreads();
  m = fmaxf(fmaxf(red[0], red[1]), fmaxf(red[2], red[3]));

  float s = 0.f;
#pragma unroll
  for (int j = 0; j < 4; ++j) { v0[j] = __expf(v0[j] - m); s += v0[j]; }
#pragma unroll
  for (int j = 0; j < 4; ++j) { v1[j] = __expf(v1[j] - m); s += v1[j]; }
#pragma unroll
  for (int off = 32; off; off >>= 1) s += __shfl_xor(s, off, 64);
  if (lane == 0) red[4 + wv] = s;
  __syncthreads();
  s = (red[4] + red[5]) + (red[6] + red[7]);
  float inv = 1.f / s;

  const int4* mrow = (const int4*)(mask + (size_t)q * Sc);
  int4 k0 = mrow[tid * 2], k1 = mrow[tid * 2 + 1];
  f32x4 w0, w1;
  w0[0] = k0.x ? v0[0] * inv : 0.f;
  w0[1] = k0.y ? v0[1] * inv : 0.f;
  w0[2] = k0.z ? v0[2] * inv : 0.f;
  w0[3] = k0.w ? v0[3] * inv : 0.f;
  w1[0] = k1.x ? v1[0] * inv : 0.f;
  w1[1] = k1.y ? v1[1] * inv : 0.f;
  w1[2] = k1.z ? v1[2] * inv : 0.f;
  w1[3] = k1.w ? v1[3] * inv : 0.f;
  ((f32x4*)row)[tid * 2] = w0;
  ((f32x4*)row)[tid * 2 + 1] = w1;
}

// ---------------------------------------------------------------------------
extern "C" void kernel_launch(void* const* d_in, const int* in_sizes, int n_in,
                              void* d_out, int out_size, void* d_ws, size_t ws_size,
                              hipStream_t stream) {
  (void)in_sizes; (void)n_in; (void)out_size; (void)ws_size;

  const float* x  = (const float*)d_in[0];
  const int* mask = (const int*)d_in[1];
  const float* Wq = (const float*)d_in[2];
  const float* bq = (const float*)d_in[3];
  const float* Wk = (const float*)d_in[4];
  const float* bk = (const float*)d_in[5];
  const float* Wv = (const float*)d_in[6];
  const float* bv = (const float*)d_in[7];
  const float* Wo = (const float*)d_in[8];
  const float* bo = (const float*)d_in[9];

  float* out = (float*)d_out;
  float* wts = out + (size_t)Bc * Sc * Ec;  // weights output region [B,H,S,S]

  // workspace layout (bf16 tensors), total ~50.3 MB
  unsigned short* xb    = (unsigned short*)d_ws;
  unsigned short* WqT   = xb  + (size_t)Bc * Sc * Ec;
  unsigned short* WkT   = WqT + (size_t)Ec * Ec;
  unsigned short* WvT   = WkT + (size_t)Ec * Ec;
  unsigned short* WoT   = WvT + (size_t)Ec * Ec;
  unsigned short* Qb    = WoT + (size_t)Ec * Ec;
  unsigned short* Kb    = Qb  + (size_t)Bc * Sc * Ec;
  unsigned short* Vt    = Kb  + (size_t)Bc * Sc * Ec;   // [B][H][DK][S]
  unsigned short* attnb = Vt  + (size_t)Bc * Sc * Ec;   // [B*S][E]

  // converts
  cvt_x_k<<<(Bc * Sc * Ec) / 8 / 256, 256, 0, stream>>>(x, xb);
  dim3 tg(Ec / 32, Ec / 32);
  cvt_wt_k<<<tg, 256, 0, stream>>>(Wq, WqT);
  cvt_wt_k<<<tg, 256, 0, stream>>>(Wk, WkT);
  cvt_wt_k<<<tg, 256, 0, stream>>>(Wv, WvT);
  cvt_wt_k<<<tg, 256, 0, stream>>>(Wo, WoT);

  // projections: [4096,1024] @ WT[1024,1024] -> bf16
  dim3 gP(Ec / 128, (Bc * Sc) / 128, 1);
  gemm_k<128, 128, false, 0><<<gP, 256, 0, stream>>>(
      xb, WqT, Qb, bq, Ec, Ec, Ec, Ec, 0, 0, 0, 0, 0, 0, 1.f);
  gemm_k<128, 128, false, 0><<<gP, 256, 0, stream>>>(
      xb, WkT, Kb, bk, Ec, Ec, Ec, Ec, 0, 0, 0, 0, 0, 0, 1.f);
  gemm_k<128, 128, false, 1><<<gP, 256, 0, stream>>>(
      xb, WvT, Vt, bv, Ec, Ec, Ec, Ec, 0, 0, 0, 0, 0, 0, 1.f);

  // scores: per (b,h): Q[S,64] @ K[S,64]^T * 0.125 -> fp32 weights region
  dim3 gS(Sc / 128, Sc / 128, Bc * Hc);
  gemm_k<128, 128, false, 2><<<gS, 256, 0, stream>>>(
      Qb, Kb, wts, nullptr, DKc, Ec, Ec, Sc,
      (long)Sc * Ec, DKc, (long)Sc * Ec, DKc,
      (long)Hc * Sc * Sc, (long)Sc * Sc, 0.125f);

  // softmax + post-softmax masking (in place on weights region)
  dim3 gSM(Sc, Bc * Hc);
  softmax_mask_k<<<gSM, 256, 0, stream>>>(wts, mask);

  // PV: weights[S,S] (fp32, staged->bf16) @ Vt[64,S]^T -> attn bf16 [B*S][E]
  dim3 gPV(1, Sc / 128, Bc * Hc);
  gemm_k<128, 64, true, 0><<<gPV, 256, 0, stream>>>(
      wts, Vt, attnb, nullptr, Sc, Sc, Sc, Ec,
      (long)Hc * Sc * Sc, (long)Sc * Sc,
      (long)Hc * DKc * Sc, (long)DKc * Sc,
      (long)Sc * Ec, DKc, 1.f);

  // out = attn @ Wo + bo -> fp32
  gemm_k<128, 128, false, 3><<<gP, 256, 0, stream>>>(
      attnb, WoT, out, bo, Ec, Ec, Ec, Ec, 0, 0, 0, 0, 0, 0, 1.f);
}